// Round 1
// 1262.846 us; speedup vs baseline: 1.0548x; 1.0548x over previous
//
#include <hip/hip_runtime.h>
#include <stdint.h>

// Pipeline (round 3): block-role fusion to overlap the two independent chains
//  L1  k_setup      : rowops (x->xhi/xlo bf16 split, sq) || transpose (x->xT,hT f32 + hT8 fp8)
//  L2  k_gram_adj   : gram (VALU/MFMA, L2-resident) || adjcvt (HBM 400MB->fp8) -- complementary pipes
//  L3  k_gemm_merge : dense gemm0 (fp8 split-K=8, bf16 parts) || knn exact-merge
//  L4  k_red_knn    : reduce0 || knnprop t0
//  L5  k_gemm_knn   : gemm1 || knnprop t1
//  L6  k_red_knn    : reduce1 || knnprop t2
//  L7  k_gemm_knn   : gemm2 || knnprop t3
//  L8  k_red_knn    : reduce2 || knnprop t4
//  L9..L12          : gemm3, reduce3, gemm4, reduce4 (kNN chain exhausted)
//  L13 k_headall    : enc(h1) + enc(h2) + zres fused, wave-per-row
//  L14 k_out2       : res @ res^T via bf16 MFMA
// parts now bf16 (halves split-K round-trip); cand and parts no longer alias.

typedef unsigned short u16;
typedef unsigned int u32;
typedef unsigned char u8;

#define N_NODES 10000
#define NPAD    10112   // 79*128
#define KPAD    10240   // 8*1280
#define JPAD    10240
#define NF      128
#define NH      64
#define CAP     96
#define ADJ_SCALE 4096.0f
#define ADJ_INV   (0.5f / 4096.0f)

#define GRAM_BLKS  632   // 158*4
#define ADJ_BLKS   1024
#define GEMM_BLKS  632   // 79*8
#define MERGE_BLKS 2500
#define RED_BLKS   1280
#define KNNP_BLKS  2500

using short8 = __attribute__((ext_vector_type(8))) short;
using f32x4  = __attribute__((ext_vector_type(4))) float;
using u16x4  = __attribute__((ext_vector_type(4))) unsigned short;

__device__ __forceinline__ u16 f2bf(float f) {
  u32 u = __float_as_uint(f);
  u += 0x7FFFu + ((u >> 16) & 1u);
  return (u16)(u >> 16);
}
__device__ __forceinline__ float bf2f(u16 h) { return __uint_as_float(((u32)h) << 16); }

__device__ __forceinline__ u32 pk4_fp8(float a, float b, float c, float d) {
  int v = __builtin_amdgcn_cvt_pk_fp8_f32(a, b, 0, false);
  v = __builtin_amdgcn_cvt_pk_fp8_f32(c, d, v, true);
  return (u32)v;
}

__device__ __forceinline__ void g2lds16(const void* g, void* l) {
  __builtin_amdgcn_global_load_lds((const __attribute__((address_space(1))) void*)g,
                                   (__attribute__((address_space(3))) void*)l, 16, 0, 0);
}

// ---------------- L1: rowops || transpose(+pack8) ----------------

__global__ __launch_bounds__(256) void k_setup(const float* __restrict__ x,
    u16* __restrict__ xhi, u16* __restrict__ xlo, float* __restrict__ sq,
    float* __restrict__ xTf, float* __restrict__ hTf, u8* __restrict__ hT8) {
  __shared__ float tile[32][33];
  int bid = blockIdx.x;
  if (bid < 2560) {
    // rowops: x -> hi/lo bf16 split + squared norms (pad rows sq=1e30)
    int w = threadIdx.x >> 6, lane = threadIdx.x & 63;
    int row = bid * 4 + w;
    if (row >= JPAD) return;
    int f = lane * 2;
    if (row < N_NODES) {
      float2 v = *(const float2*)(x + (size_t)row * NF + f);
      u16 h0 = f2bf(v.x), h1 = f2bf(v.y);
      float l0 = v.x - bf2f(h0), l1 = v.y - bf2f(h1);
      u16 e0 = f2bf(l0), e1 = f2bf(l1);
      *(u32*)(xhi + (size_t)row * NF + f) = (u32)h0 | ((u32)h1 << 16);
      *(u32*)(xlo + (size_t)row * NF + f) = (u32)e0 | ((u32)e1 << 16);
      float s = v.x * v.x + v.y * v.y;
#pragma unroll
      for (int o = 32; o > 0; o >>= 1) s += __shfl_xor(s, o);
      if (lane == 0) sq[row] = s;
    } else {
      *(u32*)(xhi + (size_t)row * NF + f) = 0u;
      *(u32*)(xlo + (size_t)row * NF + f) = 0u;
      if (lane == 0) sq[row] = 1.0e30f;
    }
  } else {
    // transpose: x -> x^T f32, h^T f32 init, h^T fp8 init
    int id2 = bid - 2560;
    int k0 = (id2 % 320) * 32, f0 = (id2 / 320) * 32;
    int c = threadIdx.x & 31, r4 = threadIdx.x >> 5;
#pragma unroll
    for (int i = 0; i < 4; i++) {
      int r = r4 + i * 8;
      int k = k0 + r;
      float v = 0.f;
      if (k < N_NODES) v = x[(size_t)k * NF + f0 + c];
      tile[r][c] = v;
    }
    __syncthreads();
#pragma unroll
    for (int i = 0; i < 4; i++) {
      int r = r4 + i * 8;
      int f = f0 + r;
      int k = k0 + c;
      float v = tile[c][r];
      size_t idx = (size_t)f * KPAD + k;
      xTf[idx] = v; hTf[idx] = v;
      hT8[idx] = (u8)(__builtin_amdgcn_cvt_pk_fp8_f32(v, 0.f, 0, false) & 0xff);
    }
  }
}

// ---------------- gram role (kNN candidate filter) ----------------

__device__ __forceinline__ void dev_gram(int bx, int split,
    u16* shi, u16* slo, float* ssq,
    const u16* __restrict__ xhi, const u16* __restrict__ xlo,
    const float* __restrict__ sqg, float2* __restrict__ cand, u32* __restrict__ cnts) {
  const int tid = threadIdx.x, w = tid >> 6, lane = tid & 63;
  const int l15 = lane & 15, g = lane >> 4;
  const int q = bx * 64 + w * 16 + l15;
  const size_t cbase = ((size_t)q * 16 + split * 4 + g) * CAP;

  short8 bh[4], bl[4];
#pragma unroll
  for (int ks = 0; ks < 4; ks++) {
    size_t off = (size_t)q * NF + ks * 32 + g * 8;
    bh[ks] = *(const short8*)(xhi + off);
    bl[ks] = *(const short8*)(xlo + off);
  }
  float t4[4] = {3.0e38f, 3.0e38f, 3.0e38f, 3.0e38f};
  float thr = 3.0e38f;
  u32 cnt = 0;

  for (int ch = 0; ch < 40; ch++) {
    int jbase = split * 2560 + ch * 64;
    __syncthreads();
#pragma unroll
    for (int r = 0; r < 4; r++) {
      int s = r * 256 + tid;
      int row = s >> 4, u = s & 15;
      int uu = u ^ (row & 7);
      size_t goff = (size_t)(jbase + row) * NF + uu * 8;
      g2lds16(xhi + goff, (void*)(shi + ((s & ~63) << 3)));
      g2lds16(xlo + goff, (void*)(slo + ((s & ~63) << 3)));
    }
    if (tid < 64) ssq[tid] = sqg[jbase + tid];
    __syncthreads();

#pragma unroll
    for (int sub = 0; sub < 4; sub++) {
      f32x4 acc = {0.f, 0.f, 0.f, 0.f};
#pragma unroll
      for (int ks = 0; ks < 4; ks++) {
        int row = sub * 16 + l15;
        int uu = ((ks * 4 + g) ^ (row & 7));
        int idx = row * 128 + uu * 8;
        short8 ah = *(const short8*)(shi + idx);
        short8 al = *(const short8*)(slo + idx);
        acc = __builtin_amdgcn_mfma_f32_16x16x32_bf16(ah, bh[ks], acc, 0, 0, 0);
        acc = __builtin_amdgcn_mfma_f32_16x16x32_bf16(ah, bl[ks], acc, 0, 0, 0);
        acc = __builtin_amdgcn_mfma_f32_16x16x32_bf16(al, bh[ks], acc, 0, 0, 0);
      }
      f32x4 sv = *(const f32x4*)(ssq + sub * 16 + g * 4);
      int jb = jbase + sub * 16 + g * 4;
#pragma unroll
      for (int reg = 0; reg < 4; reg++) {
        int j = jb + reg;
        float dd = sv[reg] - 2.0f * acc[reg];
        dd = (j == q) ? 3.0e38f : dd;
        // wave-uniform skip: once thr converges, almost no lane qualifies.
        // dd<t4[3] implies dd<thr (t4[3]<=thr), so skipping is exact.
        if (__any(dd < thr)) {
          if (dd < thr) {
            if (cnt < CAP) cand[cbase + cnt] = make_float2(dd, __int_as_float(j));
            cnt++;
          }
          bool c0 = dd < t4[0], c1 = dd < t4[1], c2 = dd < t4[2], c3 = dd < t4[3];
          t4[3] = c2 ? t4[2] : (c3 ? dd : t4[3]);
          t4[2] = c1 ? t4[1] : (c2 ? dd : t4[2]);
          t4[1] = c0 ? t4[0] : (c1 ? dd : t4[1]);
          t4[0] = c0 ? dd : t4[0];
        }
      }
      float m = t4[3];
      m = fminf(m, 3.0e38f);
      m = fmaxf(m, __shfl_xor(m, 16));
      m = fmaxf(m, __shfl_xor(m, 32));
      thr = m;
    }
  }
  cnts[(size_t)q * 16 + split * 4 + g] = (cnt < CAP) ? cnt : CAP;
}

// ---------------- adjcvt role ----------------

__device__ __forceinline__ void dev_adjcvt(int rb, const float* __restrict__ adj,
                                           u8* __restrict__ out) {
  const int UNITS = NPAD * (KPAD / 8);
  for (int u = rb * 256 + (int)threadIdx.x; u < UNITS; u += ADJ_BLKS * 256) {
    int r = u / (KPAD / 8);
    int c = (u - r * (KPAD / 8)) * 8;
    float v[8];
    if (r < N_NODES && c + 7 < N_NODES) {
      const float* p = adj + (size_t)r * N_NODES + c;
      float4 a = *(const float4*)p;
      float4 b = *(const float4*)(p + 4);
      v[0]=a.x; v[1]=a.y; v[2]=a.z; v[3]=a.w;
      v[4]=b.x; v[5]=b.y; v[6]=b.z; v[7]=b.w;
    } else {
#pragma unroll
      for (int t = 0; t < 8; t++) {
        int cc = c + t;
        v[t] = (r < N_NODES && cc < N_NODES) ? adj[(size_t)r * N_NODES + cc] : 0.f;
      }
    }
#pragma unroll
    for (int t = 0; t < 8; t++) v[t] *= ADJ_SCALE;
    uint2 pk;
    pk.x = pk4_fp8(v[0], v[1], v[2], v[3]);
    pk.y = pk4_fp8(v[4], v[5], v[6], v[7]);
    *(uint2*)(out + (size_t)r * KPAD + c) = pk;
  }
}

// ---------------- L2: gram || adjcvt ----------------

__global__ __launch_bounds__(256) void k_gram_adj(const u16* __restrict__ xhi,
    const u16* __restrict__ xlo, const float* __restrict__ sqg,
    float2* __restrict__ cand, u32* __restrict__ cnts,
    const float* __restrict__ adj, u8* __restrict__ adj8) {
  __shared__ __align__(16) u8 smem[33024];
  int bid = blockIdx.x;
  if (bid < GRAM_BLKS) {
    dev_gram(bid % 158, bid / 158, (u16*)smem, (u16*)(smem + 16384),
             (float*)(smem + 32768), xhi, xlo, sqg, cand, cnts);
  } else {
    dev_adjcvt(bid - GRAM_BLKS, adj, adj8);
  }
}

// ---------------- gemm role (fp8 split-K=8, bf16 parts) ----------------

__device__ __forceinline__ void dev_gemm(int rid, u8* As, u8* Bs,
    const u8* __restrict__ adj8, const u8* __restrict__ hT8, u16* __restrict__ parts16) {
  const int tid = threadIdx.x, w = tid >> 6, lane = tid & 63;
  const int l15 = lane & 15, g = lane >> 4;
  const int m0 = (rid % 79) * 128;
  const int split = rid / 79;
  const int wm = (w & 1) * 64, wn = (w >> 1) * 64;

  f32x4 zero = {0.f, 0.f, 0.f, 0.f};
  f32x4 acc[4][4];
#pragma unroll
  for (int mi = 0; mi < 4; mi++)
#pragma unroll
    for (int ni = 0; ni < 4; ni++) acc[mi][ni] = zero;

  for (int it = 0; it < 20; it++) {
    int kk = split * 1280 + it * 64;
    __syncthreads();
#pragma unroll
    for (int r = 0; r < 2; r++) {
      int s = r * 256 + tid;
      int row = s >> 2, u = s & 3;
      int uu = u ^ ((row >> 1) & 3);
      g2lds16(adj8 + (size_t)(m0 + row) * KPAD + kk + uu * 16, (void*)(As + ((s & ~63) << 4)));
    }
#pragma unroll
    for (int r = 0; r < 2; r++) {
      int s = r * 256 + tid;
      int row = s >> 2, u = s & 3;
      int uu = u ^ ((row >> 1) & 3);
      g2lds16(hT8 + (size_t)row * KPAD + kk + uu * 16, (void*)(Bs + ((s & ~63) << 4)));
    }
    __syncthreads();
#pragma unroll
    for (int ks = 0; ks < 2; ks++) {
      long af[4], bf[4];
#pragma unroll
      for (int mi = 0; mi < 4; mi++) {
        int row = wm + mi * 16 + l15;
        int u = (ks * 2 + (g >> 1)) ^ ((row >> 1) & 3);
        af[mi] = *(const long*)(As + row * 64 + u * 16 + (g & 1) * 8);
      }
#pragma unroll
      for (int ni = 0; ni < 4; ni++) {
        int row = wn + ni * 16 + l15;
        int u = (ks * 2 + (g >> 1)) ^ ((row >> 1) & 3);
        bf[ni] = *(const long*)(Bs + row * 64 + u * 16 + (g & 1) * 8);
      }
#pragma unroll
      for (int mi = 0; mi < 4; mi++)
#pragma unroll
        for (int ni = 0; ni < 4; ni++)
          acc[mi][ni] = __builtin_amdgcn_mfma_f32_16x16x32_fp8_fp8(af[mi], bf[ni], acc[mi][ni], 0, 0, 0);
    }
  }
#pragma unroll
  for (int mi = 0; mi < 4; mi++) {
#pragma unroll
    for (int ni = 0; ni < 4; ni++) {
      int n = wn + ni * 16 + l15;
      int m = m0 + wm + mi * 16 + g * 4;
      f32x4 a = acc[mi][ni];
      u16x4 pk = { f2bf(a[0]), f2bf(a[1]), f2bf(a[2]), f2bf(a[3]) };
      *(u16x4*)(parts16 + (size_t)(split * 128 + n) * NPAD + m) = pk;
    }
  }
}

// ---------------- merge role (exact top-16 per query) ----------------

__device__ __forceinline__ void dev_merge(int rid, const float2* __restrict__ cand,
    const u32* __restrict__ cnts, int* __restrict__ knn) {
  int w = threadIdx.x >> 6, lane = threadIdx.x & 63;
  int q = rid * 4 + w;
  if (q >= N_NODES) return;
  int r = lane >> 2, s = lane & 3;
  int cnt = (int)cnts[(size_t)q * 16 + r];
  const float2* cv = cand + ((size_t)q * 16 + r) * CAP;

  float t[16]; int ti[16];
#pragma unroll
  for (int i = 0; i < 16; i++) { t[i] = 3.0e38f; ti[i] = -1; }
  for (int e = s; e < cnt; e += 4) {
    float2 v = cv[e];
    float dd = v.x; int j = __float_as_int(v.y);
    if (j == q) continue;
    if (dd < t[15]) {
#pragma unroll
      for (int i = 15; i >= 1; --i) {
        bool ltp = dd < t[i - 1];
        bool ltc = dd < t[i];
        t[i]  = ltp ? t[i - 1] : (ltc ? dd : t[i]);
        ti[i] = ltp ? ti[i - 1] : (ltc ? j : ti[i]);
      }
      if (dd < t[0]) { t[0] = dd; ti[0] = j; }
    }
  }
  int myout = -1;
#pragma unroll
  for (int round = 0; round < 16; round++) {
    float d0 = t[0]; int j0 = ti[0];
#pragma unroll
    for (int off = 32; off > 0; off >>= 1) {
      float dn = __shfl_xor(d0, off); int jn = __shfl_xor(j0, off);
      bool take = (dn < d0) || (dn == d0 && jn < j0);
      d0 = take ? dn : d0; j0 = take ? jn : j0;
    }
    if (ti[0] == j0) {
#pragma unroll
      for (int i = 0; i < 15; i++) { t[i] = t[i + 1]; ti[i] = ti[i + 1]; }
      t[15] = 3.0e38f; ti[15] = -1;
    }
    if (lane == round) myout = j0;
  }
  if (lane < 16) knn[q * 16 + lane] = myout;
}

// ---------------- knnprop role ----------------

__device__ __forceinline__ void dev_knnprop(int rid, const float* __restrict__ src,
    const float* __restrict__ x, const int* __restrict__ knn, float* __restrict__ dst) {
  int w = threadIdx.x >> 6, lane = threadIdx.x & 63;
  int row = rid * 4 + w;
  if (row >= N_NODES) return;
  int f = lane * 2;
  float a0 = 0.f, a1 = 0.f;
#pragma unroll
  for (int nb = 0; nb < 16; nb++) {
    int j = knn[row * 16 + nb];
    float2 v = *(const float2*)(src + (size_t)j * NF + f);
    a0 += v.x; a1 += v.y;
  }
  float2 xv = *(const float2*)(x + (size_t)row * NF + f);
  float2 o;
  o.x = a0 * (0.5f / 16.f) + 0.5f * xv.x;
  o.y = a1 * (0.5f / 16.f) + 0.5f * xv.y;
  *(float2*)(dst + (size_t)row * NF + f) = o;
}

// ---------------- reduce role (bf16 parts -> h fp32 + fp8) ----------------

__device__ __forceinline__ void dev_reduce(int rid, const u16* __restrict__ parts16,
    const float* __restrict__ xTf, float* __restrict__ hTf, u8* __restrict__ hT8) {
  int idx = (rid * 256 + (int)threadIdx.x) * 4;
  int n = idx / KPAD;
  int k = idx - n * KPAD;
  float4 h = {0.f, 0.f, 0.f, 0.f};
  if (k < NPAD) {
    float s0 = 0.f, s1 = 0.f, s2 = 0.f, s3 = 0.f;
#pragma unroll
    for (int sp = 0; sp < 8; sp++) {
      u16x4 v = *(const u16x4*)(parts16 + (size_t)(sp * 128 + n) * NPAD + k);
      s0 += bf2f(v[0]); s1 += bf2f(v[1]); s2 += bf2f(v[2]); s3 += bf2f(v[3]);
    }
    float4 xv = *(const float4*)(xTf + (size_t)n * KPAD + k);
    h.x = ADJ_INV * s0 + 0.5f * xv.x;
    h.y = ADJ_INV * s1 + 0.5f * xv.y;
    h.z = ADJ_INV * s2 + 0.5f * xv.z;
    h.w = ADJ_INV * s3 + 0.5f * xv.w;
  }
  *(float4*)(hTf + (size_t)n * KPAD + k) = h;
  *(u32*)(hT8 + (size_t)n * KPAD + k) = pk4_fp8(h.x, h.y, h.z, h.w);
}

// ---------------- fused launches ----------------

__global__ __launch_bounds__(256) void k_gemm_merge(const u8* __restrict__ adj8,
    const u8* __restrict__ hT8, u16* __restrict__ parts16,
    const float2* __restrict__ cand, const u32* __restrict__ cnts, int* __restrict__ knn) {
  __shared__ __align__(16) u8 smem[16384];
  int bid = blockIdx.x;
  if (bid < GEMM_BLKS) dev_gemm(bid, smem, smem + 8192, adj8, hT8, parts16);
  else                 dev_merge(bid - GEMM_BLKS, cand, cnts, knn);
}

__global__ __launch_bounds__(256) void k_gemm_knn(const u8* __restrict__ adj8,
    const u8* __restrict__ hT8, u16* __restrict__ parts16,
    const float* __restrict__ src, const float* __restrict__ x,
    const int* __restrict__ knn, float* __restrict__ dst) {
  __shared__ __align__(16) u8 smem[16384];
  int bid = blockIdx.x;
  if (bid < GEMM_BLKS) dev_gemm(bid, smem, smem + 8192, adj8, hT8, parts16);
  else                 dev_knnprop(bid - GEMM_BLKS, src, x, knn, dst);
}

__global__ __launch_bounds__(256) void k_red_knn(const u16* __restrict__ parts16,
    const float* __restrict__ xTf, float* __restrict__ hTf, u8* __restrict__ hT8,
    const float* __restrict__ src, const float* __restrict__ x,
    const int* __restrict__ knn, float* __restrict__ dst) {
  int bid = blockIdx.x;
  if (bid < RED_BLKS) dev_reduce(bid, parts16, xTf, hTf, hT8);
  else                dev_knnprop(bid - RED_BLKS, src, x, knn, dst);
}

// ---------------- encoder/decoder tail, fused ----------------

__global__ __launch_bounds__(256) void k_headall(const float* __restrict__ hTf,
    const float* __restrict__ h2, const float* __restrict__ Wenc, const float* __restrict__ benc,
    const float* __restrict__ Wenc2, const float* __restrict__ benc2,
    const float* __restrict__ Wdec, const float* __restrict__ bdec,
    float* __restrict__ out0, float* __restrict__ out1, u16* __restrict__ resb) {
  int w = threadIdx.x >> 6, o = threadIdx.x & 63;
  int row = blockIdx.x * 4 + w;
  if (row >= NPAD) return;
  if (row >= N_NODES) {
    *(u32*)(resb + (size_t)row * NF + o * 2) = 0u;
    return;
  }
  float a1 = benc[o], a2 = benc[o];
#pragma unroll 8
  for (int f = 0; f < NF; f++) {
    float wv = Wenc[f * NH + o];
    a1 += hTf[(size_t)f * KPAD + row] * wv;
    a2 += h2[(size_t)row * NF + f] * wv;
  }
  a1 = fmaxf(a1, 0.f); a2 = fmaxf(a2, 0.f);
  out0[(size_t)row * NH + o] = a1;
  out1[(size_t)row * NH + o] = a2;
  float z1 = benc2[o], z2 = benc2[o];
#pragma unroll 8
  for (int c = 0; c < NH; c++) {
    float wv = Wenc2[c * NH + o];
    z1 += __shfl(a1, c) * wv;
    z2 += __shfl(a2, c) * wv;
  }
  z1 = fmaxf(z1, 0.f); z2 = fmaxf(z2, 0.f);
  float r0 = bdec[o], r1 = bdec[o + 64];
#pragma unroll 4
  for (int c = 0; c < NH; c++) {
    float v1 = __shfl(z1, c), v2 = __shfl(z2, c);
    r0 += v1 * Wdec[c * NF + o]      + v2 * Wdec[(c + 64) * NF + o];
    r1 += v1 * Wdec[c * NF + o + 64] + v2 * Wdec[(c + 64) * NF + o + 64];
  }
  resb[(size_t)row * NF + o] = f2bf(r0);
  resb[(size_t)row * NF + o + 64] = f2bf(r1);
}

// ---------------- res @ res^T ----------------

__global__ __launch_bounds__(256) void k_out2(const u16* __restrict__ resb,
                                              float* __restrict__ out2) {
  const int tid = threadIdx.x, w = tid >> 6, lane = tid & 63;
  const int l15 = lane & 15, g = lane >> 4;
  const int m0 = blockIdx.x * 128 + (w & 1) * 64;
  const int n0 = blockIdx.y * 128 + (w >> 1) * 64;
  short8 af[4][4];
#pragma unroll
  for (int mi = 0; mi < 4; mi++)
#pragma unroll
    for (int ks = 0; ks < 4; ks++)
      af[mi][ks] = *(const short8*)(resb + (size_t)(m0 + mi * 16 + l15) * NF + ks * 32 + g * 8);
  f32x4 acc[4][4];
#pragma unroll
  for (int ni = 0; ni < 4; ni++) {
    short8 bq[4];
#pragma unroll
    for (int ks = 0; ks < 4; ks++)
      bq[ks] = *(const short8*)(resb + (size_t)(n0 + ni * 16 + l15) * NF + ks * 32 + g * 8);
#pragma unroll
    for (int mi = 0; mi < 4; mi++) {
      f32x4 a = {0.f, 0.f, 0.f, 0.f};
#pragma unroll
      for (int ks = 0; ks < 4; ks++)
        a = __builtin_amdgcn_mfma_f32_16x16x32_bf16(af[mi][ks], bq[ks], a, 0, 0, 0);
      acc[mi][ni] = a;
    }
  }
#pragma unroll
  for (int mi = 0; mi < 4; mi++) {
#pragma unroll
    for (int ni = 0; ni < 4; ni++) {
      int n = n0 + ni * 16 + l15;
      int mb = m0 + mi * 16 + g * 4;
      if (n < N_NODES) {
#pragma unroll
        for (int reg = 0; reg < 4; reg++) {
          int m = mb + reg;
          if (m < N_NODES) out2[(size_t)m * N_NODES + n] = acc[mi][ni][reg];
        }
      }
    }
  }
}

// ---------------- launch ----------------

extern "C" void kernel_launch(void* const* d_in, const int* in_sizes, int n_in,
                              void* d_out, int out_size, void* d_ws, size_t ws_size,
                              hipStream_t stream) {
  (void)in_sizes; (void)n_in; (void)out_size; (void)ws_size;
  const float* x     = (const float*)d_in[0];
  const float* adj   = (const float*)d_in[1];
  const float* Wenc  = (const float*)d_in[2];
  const float* benc  = (const float*)d_in[3];
  const float* Wenc2 = (const float*)d_in[4];
  const float* benc2 = (const float*)d_in[5];
  const float* Wdec  = (const float*)d_in[6];
  const float* bdec  = (const float*)d_in[7];

  char* ws = (char*)d_ws;
  size_t off = 0;
  auto alloc = [&](size_t bytes) {
    void* p = ws + off;
    off = (off + bytes + 255) & ~(size_t)255;
    return p;
  };
  u8*     adj8   = (u8*)    alloc((size_t)NPAD * KPAD);               // 103.5 MB
  float2* cand   = (float2*)alloc((size_t)10240 * 16 * CAP * 8);      // 125.8 MB
  u16*    parts16= (u16*)   alloc((size_t)8 * 128 * NPAD * 2);        // 20.7 MB
  float*  hTf    = (float*) alloc((size_t)128 * KPAD * 4);
  u8*     hT8    = (u8*)    alloc((size_t)128 * KPAD);
  float*  xTf    = (float*) alloc((size_t)128 * KPAD * 4);
  u16*    xhi    = (u16*)   alloc((size_t)JPAD * NF * 2);
  u16*    xlo    = (u16*)   alloc((size_t)JPAD * NF * 2);
  float*  sq     = (float*) alloc((size_t)JPAD * 4);
  u32*    cnts   = (u32*)   alloc((size_t)10240 * 16 * 4);
  int*    knn    = (int*)   alloc((size_t)N_NODES * 16 * 4);
  float*  h2a    = (float*) alloc((size_t)N_NODES * NF * 4);
  float*  h2b    = (float*) alloc((size_t)N_NODES * NF * 4);
  u16*    resb   = (u16*)   alloc((size_t)NPAD * NF * 2);

  float* out0 = (float*)d_out;            // h1 encoded [10000,64]
  float* out1 = out0 + 640000;            // h2 encoded [10000,64]
  float* out2 = out0 + 1280000;           // res@res.T  [10000,10000]

  // L1: rowops || transpose(+fp8 pack)
  k_setup<<<dim3(2560 + 1280), dim3(256), 0, stream>>>(x, xhi, xlo, sq, xTf, hTf, hT8);
  // L2: gram (compute) || adjcvt (HBM)
  k_gram_adj<<<dim3(GRAM_BLKS + ADJ_BLKS), dim3(256), 0, stream>>>(
      xhi, xlo, sq, cand, cnts, adj, adj8);
  // L3: gemm0 || merge
  k_gemm_merge<<<dim3(GEMM_BLKS + MERGE_BLKS), dim3(256), 0, stream>>>(
      adj8, hT8, parts16, cand, cnts, knn);
  // L4: reduce0 || knnprop t0 (x -> h2a)
  k_red_knn<<<dim3(RED_BLKS + KNNP_BLKS), dim3(256), 0, stream>>>(
      parts16, xTf, hTf, hT8, x, x, knn, h2a);
  // L5: gemm1 || knnprop t1 (h2a -> h2b)
  k_gemm_knn<<<dim3(GEMM_BLKS + KNNP_BLKS), dim3(256), 0, stream>>>(
      adj8, hT8, parts16, h2a, x, knn, h2b);
  // L6: reduce1 || knnprop t2 (h2b -> h2a)
  k_red_knn<<<dim3(RED_BLKS + KNNP_BLKS), dim3(256), 0, stream>>>(
      parts16, xTf, hTf, hT8, h2b, x, knn, h2a);
  // L7: gemm2 || knnprop t3 (h2a -> h2b)
  k_gemm_knn<<<dim3(GEMM_BLKS + KNNP_BLKS), dim3(256), 0, stream>>>(
      adj8, hT8, parts16, h2a, x, knn, h2b);
  // L8: reduce2 || knnprop t4 (h2b -> h2a, final h2)
  k_red_knn<<<dim3(RED_BLKS + KNNP_BLKS), dim3(256), 0, stream>>>(
      parts16, xTf, hTf, hT8, h2b, x, knn, h2a);
  // L9..L12: remaining dense hops (kNN chain done)
  k_gemm_knn<<<dim3(GEMM_BLKS), dim3(256), 0, stream>>>(
      adj8, hT8, parts16, nullptr, x, knn, nullptr);
  k_red_knn<<<dim3(RED_BLKS), dim3(256), 0, stream>>>(
      parts16, xTf, hTf, hT8, nullptr, x, knn, nullptr);
  k_gemm_knn<<<dim3(GEMM_BLKS), dim3(256), 0, stream>>>(
      adj8, hT8, parts16, nullptr, x, knn, nullptr);
  k_red_knn<<<dim3(RED_BLKS), dim3(256), 0, stream>>>(
      parts16, xTf, hTf, hT8, nullptr, x, knn, nullptr);
  // L13: encoders + decoder fused
  k_headall<<<dim3(NPAD / 4), dim3(256), 0, stream>>>(
      hTf, h2a, Wenc, benc, Wenc2, benc2, Wdec, bdec, out0, out1, resb);
  // L14: res @ res^T
  k_out2<<<dim3(79, 79), dim3(256), 0, stream>>>(resb, out2);
}